// Round 9
// baseline (1130.440 us; speedup 1.0000x reference)
//
#include <hip/hip_runtime.h>
#include <hip/hip_bf16.h>

typedef __hip_bfloat16 bf16;
typedef __attribute__((ext_vector_type(8))) short bf16x8;
typedef __attribute__((ext_vector_type(4))) float f32x4;

#define NTOK   49
#define CDIM   256
#define NHEADS 8
#define HDIM   32
#define NWIN   64
#define BWIN   4096
#define MROWS  (BWIN * NTOK)      // 200704
#define QKVC   768
#define SCALE  0.17677669529663687f

__device__ __forceinline__ unsigned short f2bf(float f) {
    unsigned int u = __float_as_uint(f);
    u += 0x7fffu + ((u >> 16) & 1u);   // RNE
    return (unsigned short)(u >> 16);
}

// ---------------------------------------------------------------------------
// Kernel 0: proj_w fp32 -> bf16 (tiny; 256x256)
// ---------------------------------------------------------------------------
__global__ __launch_bounds__(256) void cvt_wp(
    const float* __restrict__ w, bf16* __restrict__ wb)
{
    int i = blockIdx.x * 256 + threadIdx.x;   // 16384 float4s
    float4 v = ((const float4*)w)[i];
    ushort4 o;
    o.x = f2bf(v.x); o.y = f2bf(v.y); o.z = f2bf(v.z); o.w = f2bf(v.w);
    ((ushort4*)wb)[i] = o;
}

// ---------------------------------------------------------------------------
// Kernel 1: qkv = x @ qkv_w^T + qkv_b via bf16 MFMA, fused fp32->bf16 of x.
// [UNCHANGED from R7 — verified passing]
// ---------------------------------------------------------------------------
__global__ __launch_bounds__(256) void qkv_gemm_mfma(
    const float* __restrict__ X, const float* __restrict__ W,
    const float* __restrict__ bias, bf16* __restrict__ qkv)
{
    __shared__ bf16 As[128 * 64];
    __shared__ bf16 Bs[128 * 64];
    const int tid = threadIdx.x;
    const int wid = tid >> 6;
    const int ln  = tid & 63;

    const int lin   = blockIdx.y * gridDim.x + blockIdx.x;
    const int chunk = (gridDim.x * gridDim.y) >> 3;
    const int swz   = (lin & 7) * chunk + (lin >> 3);
    const int rowBase = (swz / gridDim.x) * 128;
    const int colBase = (swz % gridDim.x) * 128;

    const int wr = wid >> 1, wc = wid & 1;

    f32x4 zero = {0.f, 0.f, 0.f, 0.f};
    f32x4 acc[4][4];
#pragma unroll
    for (int i = 0; i < 4; ++i)
#pragma unroll
        for (int j = 0; j < 4; ++j) acc[i][j] = zero;

    const int srow  = ln >> 3;
    const int gslot = ln & 7;
    const int wslot = gslot ^ srow;
    const size_t aRow0 = (size_t)(rowBase + wid * 32);
    const size_t bRow0 = (size_t)(colBase + wid * 32);

    for (int k0 = 0; k0 < CDIM; k0 += 64) {
        float4 a0[4], a1[4], f0[4], f1[4];
#pragma unroll
        for (int c = 0; c < 4; ++c) {
            const float* gx = X + (aRow0 + c * 8 + srow) * CDIM + k0 + gslot * 8;
            a0[c] = *(const float4*)gx;
            a1[c] = *(const float4*)(gx + 4);
        }
#pragma unroll
        for (int c = 0; c < 4; ++c) {
            const float* gw = W + (size_t)(bRow0 + c * 8 + srow) * CDIM
                              + k0 + gslot * 8;
            f0[c] = *(const float4*)gw;
            f1[c] = *(const float4*)(gw + 4);
        }
#pragma unroll
        for (int c = 0; c < 4; ++c) {
            bf16x8 pk;
            pk[0] = (short)f2bf(a0[c].x); pk[1] = (short)f2bf(a0[c].y);
            pk[2] = (short)f2bf(a0[c].z); pk[3] = (short)f2bf(a0[c].w);
            pk[4] = (short)f2bf(a1[c].x); pk[5] = (short)f2bf(a1[c].y);
            pk[6] = (short)f2bf(a1[c].z); pk[7] = (short)f2bf(a1[c].w);
            *(bf16x8*)((char*)As + (wid * 32 + c * 8 + srow) * 128
                       + (wslot << 4)) = pk;
        }
#pragma unroll
        for (int c = 0; c < 4; ++c) {
            bf16x8 pk;
            pk[0] = (short)f2bf(f0[c].x); pk[1] = (short)f2bf(f0[c].y);
            pk[2] = (short)f2bf(f0[c].z); pk[3] = (short)f2bf(f0[c].w);
            pk[4] = (short)f2bf(f1[c].x); pk[5] = (short)f2bf(f1[c].y);
            pk[6] = (short)f2bf(f1[c].z); pk[7] = (short)f2bf(f1[c].w);
            *(bf16x8*)((char*)Bs + (wid * 32 + c * 8 + srow) * 128
                       + (wslot << 4)) = pk;
        }
        __syncthreads();
#pragma unroll
        for (int kk = 0; kk < 2; ++kk) {
            bf16x8 av[4], bv[4];
#pragma unroll
            for (int m = 0; m < 4; ++m) {
                int r = wr * 64 + m * 16 + (ln & 15);
                int g = kk * 4 + (ln >> 4);
                av[m] = *(const bf16x8*)((const char*)As +
                          (r * 128 + ((g ^ (r & 7)) << 4)));
            }
#pragma unroll
            for (int n = 0; n < 4; ++n) {
                int r = wc * 64 + n * 16 + (ln & 15);
                int g = kk * 4 + (ln >> 4);
                bv[n] = *(const bf16x8*)((const char*)Bs +
                          (r * 128 + ((g ^ (r & 7)) << 4)));
            }
#pragma unroll
            for (int m = 0; m < 4; ++m)
#pragma unroll
                for (int n = 0; n < 4; ++n)
                    acc[m][n] = __builtin_amdgcn_mfma_f32_16x16x32_bf16(
                        av[m], bv[n], acc[m][n], 0, 0, 0);
        }
        __syncthreads();
    }

    const int lq = ln >> 4;
    const int lr = ln & 15;
#pragma unroll
    for (int m = 0; m < 4; ++m) {
#pragma unroll
        for (int q = 0; q < 4; ++q) {
            int row = rowBase + wr * 64 + m * 16 + lq * 4 + q;
            int bw = row / NTOK;
            int nn = row - bw * NTOK;
            bf16* dst0 = qkv + (size_t)bw * 24 * (NTOK * HDIM) + nn * HDIM;
#pragma unroll
            for (int n = 0; n < 4; ++n) {
                int col = colBase + wc * 64 + n * 16 + lr;
                int which = col >> 8, hh = (col >> 5) & 7, dd = col & 31;
                float v = acc[m][n][q] + bias[col];
                dst0[(size_t)(which * 8 + hh) * (NTOK * HDIM) + dd] =
                    __float2bfloat16(v);
            }
        }
    }
}

// ---------------------------------------------------------------------------
// Kernel 2: MFMA attention + FUSED output projection.
// Phase 1 (per wave, heads wv and wv+4): identical to R7's verified attn —
//   QK^T via mfma(K,Q) from global, fp32 softmax in-register, attn_out fp32,
//   P bf16 -> wave-private swizzled LDS, V^T -> wave-private LDS, O = mfma(P,V)
//   kept in REGISTERS (oreg[2]) instead of stored to global.
// Phase 2: barrier; O (bf16) -> swizzled o_lds tile ALIASED over dead vt/ps;
//   barrier; out[b] = O @ proj_w^T + proj_b in-block (wave wv owns 64 cols).
// ---------------------------------------------------------------------------
__global__ __launch_bounds__(256) void attn_proj_k(
    const bf16* __restrict__ qkv, const float* __restrict__ mask,
    const float* __restrict__ bt, const bf16* __restrict__ wp,
    const float* __restrict__ pb, float* __restrict__ attn_out,
    float* __restrict__ out)
{
    const int b  = blockIdx.x;
    const int wv = threadIdx.x >> 6;
    const int ln = threadIdx.x & 63;
    const int r  = ln & 15;     // fragment row/col lane
    const int g  = ln >> 4;     // k-group 0..3

    // 48 KB arena: phase1 = vt(4x4KB) + ps(4x8KB); phase2 alias = o_lds 32KB
    __shared__ __align__(16) char smem[49152];
    char* vt = smem + wv * 4096;            // Vt[d][j], swizzled, per-wave
    char* ps = smem + 16384 + wv * 8192;    // P[i][j],  swizzled, per-wave
    __shared__ float mlds[NTOK * NTOK];     // mask window, 9604 B
    __shared__ float btlds[169 * NHEADS];   // bias table, 5408 B

    const float* mrow = mask + (size_t)(b & (NWIN - 1)) * (NTOK * NTOK);
    for (int e = threadIdx.x; e < NTOK * NTOK; e += 256) mlds[e] = mrow[e];
    for (int e = threadIdx.x; e < 169 * NHEADS; e += 256) btlds[e] = bt[e];
    __syncthreads();

    f32x4 zero = {0.f, 0.f, 0.f, 0.f};
    f32x4 oreg[2][4][2];

#pragma unroll
    for (int hh = 0; hh < 2; ++hh) {
        const int h = wv + hh * 4;
        const bf16* qp = qkv + ((size_t)b * 24 + h)      * (NTOK * HDIM);
        const bf16* kp = qkv + ((size_t)b * 24 + 8 + h)  * (NTOK * HDIM);
        const bf16* vp = qkv + ((size_t)b * 24 + 16 + h) * (NTOK * HDIM);

        // ---- Q,K fragments direct from global (rows clamped to 48) ----
        bf16x8 qf[4], kf[4];
#pragma unroll
        for (int t = 0; t < 4; ++t) {
            int qi = t * 16 + r; if (qi > 48) qi = 48;
            qf[t] = *(const bf16x8*)(qp + qi * HDIM + g * 8);
            kf[t] = *(const bf16x8*)(kp + qi * HDIM + g * 8);
        }

        // ---- stage V transposed into LDS: Vt[d][j=ln], zero pad j>=49 ----
        bf16x8 vr0 = {0,0,0,0,0,0,0,0}, vr1 = vr0, vr2 = vr0, vr3 = vr0;
        if (ln < NTOK) {
            vr0 = *(const bf16x8*)(vp + ln * HDIM);
            vr1 = *(const bf16x8*)(vp + ln * HDIM + 8);
            vr2 = *(const bf16x8*)(vp + ln * HDIM + 16);
            vr3 = *(const bf16x8*)(vp + ln * HDIM + 24);
        }
#pragma unroll
        for (int d = 0; d < 32; ++d) {
            short val = (d < 8) ? vr0[d & 7] : (d < 16) ? vr1[d & 7]
                      : (d < 24) ? vr2[d & 7] : vr3[d & 7];
            *(short*)(vt + d * 128 + ((((ln >> 3)) ^ (d & 7)) << 4)
                      + (ln & 7) * 2) = val;
        }

        // ---- QK^T: S^T tile; s[mt][nt], m=j (K rows), n=i (Q rows) ----
        f32x4 s[4][4];
#pragma unroll
        for (int mt = 0; mt < 4; ++mt)
#pragma unroll
            for (int nt = 0; nt < 4; ++nt) s[mt][nt] = zero;
#pragma unroll
        for (int mt = 0; mt < 4; ++mt)
#pragma unroll
            for (int nt = 0; nt < 4; ++nt)
                s[mt][nt] = __builtin_amdgcn_mfma_f32_16x16x32_bf16(
                    kf[mt], qf[nt], s[mt][nt], 0, 0, 0);

        // ---- bias + mask + softmax (per nt: row i = nt*16+r) ----
        float* aout = attn_out + (((size_t)b * NHEADS + h) * NTOK) * NTOK;
#pragma unroll
        for (int nt = 0; nt < 4; ++nt) {
            const int i = nt * 16 + r;
            const bool iok = (i < NTOK);
            const int ih = (i * 9363) >> 16;
            const int iw = i - ih * 7;
            float sv[4][4];
#pragma unroll
            for (int mt = 0; mt < 4; ++mt)
#pragma unroll
                for (int q = 0; q < 4; ++q) {
                    const int j = mt * 16 + g * 4 + q;
                    float v = -1e30f;
                    if (iok && j < NTOK) {
                        const int jh = (j * 9363) >> 16;
                        const int jw = j - jh * 7;
                        float bias = btlds[((ih - jh + 6) * 13 +
                                            (iw - jw + 6)) * NHEADS + h];
                        v = s[mt][nt][q] * SCALE + bias + mlds[i * NTOK + j];
                    }
                    sv[mt][q] = v;
                }
            float mx = -1e30f;
#pragma unroll
            for (int mt = 0; mt < 4; ++mt)
#pragma unroll
                for (int q = 0; q < 4; ++q) mx = fmaxf(mx, sv[mt][q]);
            mx = fmaxf(mx, __shfl_xor(mx, 16));
            mx = fmaxf(mx, __shfl_xor(mx, 32));
            float sum = 0.f;
#pragma unroll
            for (int mt = 0; mt < 4; ++mt)
#pragma unroll
                for (int q = 0; q < 4; ++q) {
                    sv[mt][q] = __expf(sv[mt][q] - mx);
                    sum += sv[mt][q];
                }
            sum += __shfl_xor(sum, 16);
            sum += __shfl_xor(sum, 32);
            const float inv = 1.0f / sum;
#pragma unroll
            for (int mt = 0; mt < 4; ++mt) {
#pragma unroll
                for (int qh = 0; qh < 2; ++qh) {
                    float p0 = sv[mt][qh * 2]     * inv;
                    float p1 = sv[mt][qh * 2 + 1] * inv;
                    const int j0 = mt * 16 + g * 4 + qh * 2;
                    if (iok) {
                        if (j0 < NTOK)     aout[(size_t)i * NTOK + j0]     = p0;
                        if (j0 + 1 < NTOK) aout[(size_t)i * NTOK + j0 + 1] = p1;
                    }
                    unsigned int pk = (unsigned int)f2bf(p0) |
                                      ((unsigned int)f2bf(p1) << 16);
                    *(unsigned int*)(ps + i * 128 +
                        (((2 * mt + (g >> 1)) ^ (r & 7)) << 4) +
                        (g & 1) * 8 + qh * 4) = pk;
                }
            }
        }

        // ---- PV: O[i][d] = sum_j P[i][j] V[j][d]  (kept in registers) ----
#pragma unroll
        for (int mt = 0; mt < 4; ++mt)
#pragma unroll
            for (int nt = 0; nt < 2; ++nt) oreg[hh][mt][nt] = zero;
#pragma unroll
        for (int ks = 0; ks < 2; ++ks) {
            bf16x8 pa[4], vb[2];
#pragma unroll
            for (int mt = 0; mt < 4; ++mt) {
                const int row = mt * 16 + r;
                pa[mt] = *(const bf16x8*)(ps + row * 128 +
                           (((ks * 4 + g) ^ (r & 7)) << 4));
            }
#pragma unroll
            for (int nt = 0; nt < 2; ++nt) {
                const int row = nt * 16 + r;
                vb[nt] = *(const bf16x8*)(vt + row * 128 +
                           (((ks * 4 + g) ^ (r & 7)) << 4));
            }
#pragma unroll
            for (int mt = 0; mt < 4; ++mt)
#pragma unroll
                for (int nt = 0; nt < 2; ++nt)
                    oreg[hh][mt][nt] = __builtin_amdgcn_mfma_f32_16x16x32_bf16(
                        pa[mt], vb[nt], oreg[hh][mt][nt], 0, 0, 0);
        }
    }

    // ==== Phase 2: fused projection ====
    __syncthreads();            // all waves done reading vt/ps
    char* ol = smem;            // o_lds[64][256] bf16, swizzled, aliases vt/ps
#pragma unroll
    for (int hh = 0; hh < 2; ++hh) {
#pragma unroll
        for (int mt = 0; mt < 4; ++mt) {
#pragma unroll
            for (int q = 0; q < 4; ++q) {
                const int row = mt * 16 + g * 4 + q;
#pragma unroll
                for (int nt = 0; nt < 2; ++nt) {
                    const int col = (wv + hh * 4) * HDIM + nt * 16 + r;
                    *(short*)(ol + row * 512 +
                              ((((col >> 3)) ^ (row & 7)) << 4) +
                              (col & 7) * 2) =
                        (short)f2bf(oreg[hh][mt][nt][q]);
                }
            }
        }
    }
    __syncthreads();            // o_lds complete

    // out[b] = O @ wp^T + pb. Wave wv owns output cols [wv*64, wv*64+64).
    const int wcol = wv * 64;
    f32x4 pacc[4][4];
#pragma unroll
    for (int rt = 0; rt < 4; ++rt)
#pragma unroll
        for (int ct = 0; ct < 4; ++ct) pacc[rt][ct] = zero;
#pragma unroll
    for (int kf = 0; kf < 8; ++kf) {
        bf16x8 av[4], bv[4];
#pragma unroll
        for (int rt = 0; rt < 4; ++rt) {
            const int row = rt * 16 + r;
            av[rt] = *(const bf16x8*)(ol + row * 512 +
                       (((kf * 4 + g) ^ (row & 7)) << 4));
        }
#pragma unroll
        for (int ct = 0; ct < 4; ++ct) {
            const int c = wcol + ct * 16 + r;
            bv[ct] = *(const bf16x8*)(wp + (size_t)c * CDIM + kf * 32 + g * 8);
        }
#pragma unroll
        for (int rt = 0; rt < 4; ++rt)
#pragma unroll
            for (int ct = 0; ct < 4; ++ct)
                pacc[rt][ct] = __builtin_amdgcn_mfma_f32_16x16x32_bf16(
                    av[rt], bv[ct], pacc[rt][ct], 0, 0, 0);
    }

    float* ob = out + (size_t)b * NTOK * CDIM;
#pragma unroll
    for (int rt = 0; rt < 4; ++rt) {
#pragma unroll
        for (int q = 0; q < 4; ++q) {
            const int row = rt * 16 + g * 4 + q;
            if (row < NTOK) {
#pragma unroll
                for (int ct = 0; ct < 4; ++ct) {
                    const int c = wcol + ct * 16 + r;
                    ob[(size_t)row * CDIM + c] = pacc[rt][ct][q] + pb[c];
                }
            }
        }
    }
}

// ---------------------------------------------------------------------------
extern "C" void kernel_launch(void* const* d_in, const int* in_sizes, int n_in,
                              void* d_out, int out_size, void* d_ws, size_t ws_size,
                              hipStream_t stream)
{
    const float* x      = (const float*)d_in[0];   // [4096,49,256]
    const float* mask   = (const float*)d_in[1];   // [64,49,49]
    const float* qkv_w  = (const float*)d_in[2];   // [768,256]
    const float* qkv_b  = (const float*)d_in[3];   // [768]
    const float* proj_w = (const float*)d_in[4];   // [256,256]
    const float* proj_b = (const float*)d_in[5];   // [256]
    const float* bt     = (const float*)d_in[6];   // [169,8]

    float* out      = (float*)d_out;                       // [4096,49,256]
    float* attn_out = out + (size_t)MROWS * CDIM;          // [4096,8,49,49]

    bf16* qkv_ws = (bf16*)d_ws;                            // [MROWS*768] bf16
    bf16* wp_b   = qkv_ws + (size_t)MROWS * QKVC;          // [256*256] bf16
    // ws footprint: 308 MB + 128 KB  (well under prior 411 MB)

    // Kernel 0: proj_w -> bf16 (tiny)
    cvt_wp<<<64, 256, 0, stream>>>(proj_w, wp_b);

    // Kernel 1: QKV projection with fused x fp32->bf16
    qkv_gemm_mfma<<<dim3(QKVC/128, MROWS/128), 256, 0, stream>>>(
        x, qkv_w, qkv_b, qkv_ws);

    // Kernel 2: attention + fused output projection (proj kernel eliminated)
    attn_proj_k<<<dim3(BWIN), 256, 0, stream>>>(qkv_ws, mask, bt, wp_b,
                                                proj_b, attn_out, out);
}